// Round 1
// baseline (6544.965 us; speedup 1.0000x reference)
//
#include <hip/hip_runtime.h>
#include <math.h>

#define BATCH 8
#define CH    128
#define HH    64
#define WW    64
#define HWSZ  (HH*WW)        // 4096
#define KK    9
#define OC27  27
#define KDIM  1152           // CH*KK

// ---------------- K0: transpose NCHW -> NHWC ----------------
__global__ void k_transpose(const float* __restrict__ in, float* __restrict__ out) {
    __shared__ float tile[32][33];
    int b  = blockIdx.z;
    int c0 = blockIdx.y * 32;
    int s0 = blockIdx.x * 32;
    int tx = threadIdx.x, ty = threadIdx.y;
    const float* inb = in  + (size_t)b * CH * HWSZ;
    float*      outb = out + (size_t)b * HWSZ * CH;
#pragma unroll
    for (int i = 0; i < 32; i += 8)
        tile[ty + i][tx] = inb[(size_t)(c0 + ty + i) * HWSZ + s0 + tx];
    __syncthreads();
#pragma unroll
    for (int i = 0; i < 32; i += 8)
        outb[(size_t)(s0 + ty + i) * CH + c0 + tx] = tile[tx][ty + i];
}

__device__ __forceinline__ float f4e(const float4& v, int e) {
    switch (e) { case 0: return v.x; case 1: return v.y; case 2: return v.z; default: return v.w; }
}

// ---------------- K1: offset+mask conv3x3 (fp32) ----------------
// om[pix][27]: ch 0..17 = offsets (linear+bias), ch 18..26 = sigmoid(mask conv)
__global__ __launch_bounds__(256) void k_offmask(
        const float* __restrict__ x_t,
        const float* __restrict__ offset_w, const float* __restrict__ offset_b,
        const float* __restrict__ mask_w,   const float* __restrict__ mask_b,
        float* __restrict__ om) {
    int gid = blockIdx.x * 256 + threadIdx.x;
    int oc  = gid & 31;
    int pix = gid >> 5;
    if (oc >= OC27) return;
    int b = pix >> 12;
    int h = (pix >> 6) & 63;
    int w = pix & 63;

    const float* tp[9];
    bool tv[9];
#pragma unroll
    for (int t = 0; t < 9; t++) {
        int y = h + t / 3 - 1;
        int x = w + t % 3 - 1;
        bool v = (y >= 0) && (y < HH) && (x >= 0) && (x < WW);
        tv[t] = v;
        int yc = v ? y : 0, xc = v ? x : 0;
        tp[t] = x_t + ((size_t)(b * HH + yc) * WW + xc) * CH;
    }

    const float* wrow;
    float acc;
    if (oc < 18) { wrow = offset_w + (size_t)oc * KDIM;        acc = offset_b[oc]; }
    else         { wrow = mask_w   + (size_t)(oc - 18) * KDIM; acc = mask_b[oc - 18]; }

    for (int c4 = 0; c4 < 32; c4++) {
        float4 xv[9];
#pragma unroll
        for (int t = 0; t < 9; t++)
            xv[t] = tv[t] ? *(const float4*)(tp[t] + c4 * 4) : make_float4(0.f, 0.f, 0.f, 0.f);
        const float4* wp = (const float4*)(wrow + c4 * 36);
        float4 wv[9];
#pragma unroll
        for (int i = 0; i < 9; i++) wv[i] = wp[i];
#pragma unroll
        for (int j = 0; j < 36; j++) {
            int i = j / 4, e = j % 4;   // weight element
            int cc = j / 9, t = j % 9;  // j = c*9 + t within this c4 group
            acc = fmaf(f4e(wv[i], e), f4e(xv[t], cc), acc);
        }
    }
    if (oc >= 18) acc = 1.0f / (1.0f + expf(-acc));
    om[(size_t)pix * OC27 + oc] = acc;
}

// ---------------- K2: deformable gather + 128x1152 contraction ----------------
#define TP 16   // pixels per block (one row segment, same b,h)

__global__ __launch_bounds__(256) void k_deform(
        const float* __restrict__ x_t,
        const float* __restrict__ om,
        const float* __restrict__ weight,
        const float* __restrict__ bias,
        float* __restrict__ out) {
    __shared__ float s[TP * KDIM];         // [pix][c*9+k]  (73728 B)
    __shared__ int   pI[TP * KK][4];
    __shared__ float pW[TP * KK][4];

    int tid = threadIdx.x;
    int p0  = blockIdx.x * TP;
    int b   = p0 >> 12;
    int h   = (p0 >> 6) & 63;
    int w0  = p0 & 63;

    // Phase A: bilinear params per (pixel, k)
    if (tid < TP * KK) {
        int pixl = tid / KK;
        int k    = tid % KK;
        int p    = p0 + pixl;
        int w    = w0 + pixl;
        const float* omp = om + (size_t)p * OC27;
        float dy = omp[2 * k], dx = omp[2 * k + 1], m = omp[18 + k];
        float py = (float)h + (float)(k / 3 - 1) + dy;
        float px = (float)w + (float)(k % 3 - 1) + dx;
        float y0f = floorf(py), x0f = floorf(px);
        float ly = py - y0f, lx = px - x0f;
        int y0 = (int)y0f, x0 = (int)x0f;
        int y1 = y0 + 1,   x1 = x0 + 1;
        bool vy0 = (y0 >= 0) && (y0 < HH), vy1 = (y1 >= 0) && (y1 < HH);
        bool vx0 = (x0 >= 0) && (x0 < WW), vx1 = (x1 >= 0) && (x1 < WW);
        int yc0 = min(max(y0, 0), HH - 1), yc1 = min(max(y1, 0), HH - 1);
        int xc0 = min(max(x0, 0), WW - 1), xc1 = min(max(x1, 0), WW - 1);
        int rb = b * HH;
        pI[tid][0] = ((rb + yc0) * WW + xc0) * CH;
        pI[tid][1] = ((rb + yc0) * WW + xc1) * CH;
        pI[tid][2] = ((rb + yc1) * WW + xc0) * CH;
        pI[tid][3] = ((rb + yc1) * WW + xc1) * CH;
        pW[tid][0] = (1.f - ly) * (1.f - lx) * m * ((vy0 && vx0) ? 1.f : 0.f);
        pW[tid][1] = (1.f - ly) * lx         * m * ((vy0 && vx1) ? 1.f : 0.f);
        pW[tid][2] = ly         * (1.f - lx) * m * ((vy1 && vx0) ? 1.f : 0.f);
        pW[tid][3] = ly         * lx         * m * ((vy1 && vx1) ? 1.f : 0.f);
    }
    __syncthreads();

    // Phase B: build s[pix][c*9+k] = mask-weighted bilinear sample
    for (int v = tid; v < TP * KK * CH; v += 256) {
        int k    = v >> 11;          // v / 2048
        int r    = v & 2047;
        int pixl = r >> 7;
        int c    = r & 127;
        int pk   = pixl * KK + k;
        float sum = pW[pk][0] * x_t[pI[pk][0] + c]
                  + pW[pk][1] * x_t[pI[pk][1] + c]
                  + pW[pk][2] * x_t[pI[pk][2] + c]
                  + pW[pk][3] * x_t[pI[pk][3] + c];
        s[pixl * KDIM + c * KK + k] = sum;
    }
    __syncthreads();

    // Phase C: y[o, pix] = sum_j s[pix][j] * weight[o][j]  (2 o x 4 pix per thread)
    int o0 = (tid & 63) * 2;
    int pq = tid >> 6;              // 0..3 -> pixels pq*4 .. pq*4+3
    const float4* wa4 = (const float4*)(weight + (size_t)o0 * KDIM);
    const float4* wb4 = (const float4*)(weight + (size_t)(o0 + 1) * KDIM);
    const float4* s0 = (const float4*)(s + (pq * 4 + 0) * KDIM);
    const float4* s1 = (const float4*)(s + (pq * 4 + 1) * KDIM);
    const float4* s2 = (const float4*)(s + (pq * 4 + 2) * KDIM);
    const float4* s3 = (const float4*)(s + (pq * 4 + 3) * KDIM);

    float a00 = 0.f, a01 = 0.f, a02 = 0.f, a03 = 0.f;
    float a10 = 0.f, a11 = 0.f, a12 = 0.f, a13 = 0.f;
    for (int j = 0; j < KDIM / 4; j++) {
        float4 wa = wa4[j], wb = wb4[j];
        float4 v0 = s0[j], v1 = s1[j], v2 = s2[j], v3 = s3[j];
        a00 += wa.x * v0.x + wa.y * v0.y + wa.z * v0.z + wa.w * v0.w;
        a01 += wa.x * v1.x + wa.y * v1.y + wa.z * v1.z + wa.w * v1.w;
        a02 += wa.x * v2.x + wa.y * v2.y + wa.z * v2.z + wa.w * v2.w;
        a03 += wa.x * v3.x + wa.y * v3.y + wa.z * v3.z + wa.w * v3.w;
        a10 += wb.x * v0.x + wb.y * v0.y + wb.z * v0.z + wb.w * v0.w;
        a11 += wb.x * v1.x + wb.y * v1.y + wb.z * v1.z + wb.w * v1.w;
        a12 += wb.x * v2.x + wb.y * v2.y + wb.z * v2.z + wb.w * v2.w;
        a13 += wb.x * v3.x + wb.y * v3.y + wb.z * v3.z + wb.w * v3.w;
    }
    float b0 = bias[o0], b1 = bias[o0 + 1];
    float* outp0 = out + (size_t)(b * CH + o0) * HWSZ + h * WW + w0 + pq * 4;
    float* outp1 = outp0 + HWSZ;
    *(float4*)outp0 = make_float4(a00 + b0, a01 + b0, a02 + b0, a03 + b0);
    *(float4*)outp1 = make_float4(a10 + b1, a11 + b1, a12 + b1, a13 + b1);
}

extern "C" void kernel_launch(void* const* d_in, const int* in_sizes, int n_in,
                              void* d_out, int out_size, void* d_ws, size_t ws_size,
                              hipStream_t stream) {
    const float* x        = (const float*)d_in[0];
    const float* offset_w = (const float*)d_in[1];
    const float* offset_b = (const float*)d_in[2];
    const float* mask_w   = (const float*)d_in[3];
    const float* mask_b   = (const float*)d_in[4];
    const float* weight   = (const float*)d_in[5];
    const float* bias     = (const float*)d_in[6];
    float* out = (float*)d_out;

    float* x_t = (float*)d_ws;                       // 8*128*64*64 = 4,194,304 floats
    float* om  = x_t + (size_t)BATCH * CH * HWSZ;    // 32768*27    =   884,736 floats

    dim3 tb(32, 8, 1);
    dim3 tg(HWSZ / 32, CH / 32, BATCH);
    k_transpose<<<tg, tb, 0, stream>>>(x, x_t);

    int npix = BATCH * HWSZ;                         // 32768
    k_offmask<<<npix * 32 / 256, 256, 0, stream>>>(x_t, offset_w, offset_b, mask_w, mask_b, om);

    k_deform<<<npix / TP, 256, 0, stream>>>(x_t, om, weight, bias, out);
}

// Round 2
// 652.598 us; speedup vs baseline: 10.0291x; 10.0291x over previous
//
#include <hip/hip_runtime.h>
#include <math.h>

#define BATCH 8
#define CH    128
#define HH    64
#define WW    64
#define HWSZ  (HH*WW)        // 4096
#define KK    9
#define OC27  27
#define KDIM  1152           // CH*KK

// ---------------- K0: transpose NCHW -> NHWC ----------------
__global__ void k_transpose(const float* __restrict__ in, float* __restrict__ out) {
    __shared__ float tile[32][33];
    int b  = blockIdx.z;
    int c0 = blockIdx.y * 32;
    int s0 = blockIdx.x * 32;
    int tx = threadIdx.x, ty = threadIdx.y;
    const float* inb = in  + (size_t)b * CH * HWSZ;
    float*      outb = out + (size_t)b * HWSZ * CH;
#pragma unroll
    for (int i = 0; i < 32; i += 8)
        tile[ty + i][tx] = inb[(size_t)(c0 + ty + i) * HWSZ + s0 + tx];
    __syncthreads();
#pragma unroll
    for (int i = 0; i < 32; i += 8)
        outb[(size_t)(s0 + ty + i) * CH + c0 + tx] = tile[tx][ty + i];
}

// ---------------- K1: offset+mask conv3x3 via LDS im2col tile ----------------
// om[pix][27]: ch 0..17 = offsets (linear+bias), ch 18..26 = sigmoid(mask conv)
#define TP1 16
#define SROW 1156   // 1152 + 4 pad floats: spreads pixel rows across bank groups

__global__ __launch_bounds__(256) void k_offmask2(
        const float* __restrict__ x_t,
        const float* __restrict__ offset_w, const float* __restrict__ offset_b,
        const float* __restrict__ mask_w,   const float* __restrict__ mask_b,
        float* __restrict__ om) {
    __shared__ float s[TP1][SROW];
    __shared__ int   base[TP1 * KK];
    __shared__ float vmul[TP1 * KK];

    int tid = threadIdx.x;
    int p0  = blockIdx.x * TP1;
    int b   = p0 >> 12;
    int h   = (p0 >> 6) & 63;
    int w0  = p0 & 63;

    // Phase A: per (pixel, tap) base index + validity
    if (tid < TP1 * KK) {
        int pixl = tid / KK, t = tid % KK;
        int w = w0 + pixl;
        int y = h + t / 3 - 1;
        int x = w + t % 3 - 1;
        bool v = (y >= 0) && (y < HH) && (x >= 0) && (x < WW);
        int yc = v ? y : 0, xc = v ? x : 0;
        base[tid] = ((b * HH + yc) * WW + xc) * CH;
        vmul[tid] = v ? 1.f : 0.f;
    }
    __syncthreads();

    // Phase B: build im2col tile s[pix][c*9+t]
    for (int v = tid; v < TP1 * KK * CH; v += 256) {
        int t    = v >> 11;
        int r    = v & 2047;
        int pixl = r >> 7;
        int c    = r & 127;
        int pk   = pixl * KK + t;
        s[pixl][c * KK + t] = vmul[pk] * x_t[base[pk] + c];
    }
    __syncthreads();

    // Phase C: 27 oc x 16 pix; thread = (oc, pixel-pair)
    if (tid < 216) {
        int oc = tid / 8;
        int pp = tid % 8;
        const float* wrow = (oc < 18) ? offset_w + (size_t)oc * KDIM
                                      : mask_w   + (size_t)(oc - 18) * KDIM;
        float bv = (oc < 18) ? offset_b[oc] : mask_b[oc - 18];
        const float4* w4 = (const float4*)wrow;
        const float4* sa = (const float4*)&s[2 * pp][0];
        const float4* sb = (const float4*)&s[2 * pp + 1][0];
        float a0 = 0.f, a1 = 0.f;
#pragma unroll 4
        for (int j = 0; j < KDIM / 4; j++) {
            float4 wv = w4[j], va = sa[j], vb = sb[j];
            a0 += wv.x * va.x + wv.y * va.y + wv.z * va.z + wv.w * va.w;
            a1 += wv.x * vb.x + wv.y * vb.y + wv.z * vb.z + wv.w * vb.w;
        }
        a0 += bv; a1 += bv;
        if (oc >= 18) {
            a0 = 1.f / (1.f + expf(-a0));
            a1 = 1.f / (1.f + expf(-a1));
        }
        om[(size_t)(p0 + 2 * pp)     * OC27 + oc] = a0;
        om[(size_t)(p0 + 2 * pp + 1) * OC27 + oc] = a1;
    }
}

// ---------------- K2: deformable gather + 128x1152 contraction ----------------
#define TP 16   // pixels per block (one row segment, same b,h)

__global__ __launch_bounds__(256) void k_deform(
        const float* __restrict__ x_t,
        const float* __restrict__ om,
        const float* __restrict__ weight,
        const float* __restrict__ bias,
        float* __restrict__ out) {
    __shared__ float s[TP * KDIM];         // [pix][c*9+k]  (73728 B)
    __shared__ int   pI[TP * KK][4];
    __shared__ float pW[TP * KK][4];

    int tid = threadIdx.x;
    int p0  = blockIdx.x * TP;
    int b   = p0 >> 12;
    int h   = (p0 >> 6) & 63;
    int w0  = p0 & 63;

    // Phase A: bilinear params per (pixel, k)
    if (tid < TP * KK) {
        int pixl = tid / KK;
        int k    = tid % KK;
        int p    = p0 + pixl;
        int w    = w0 + pixl;
        const float* omp = om + (size_t)p * OC27;
        float dy = omp[2 * k], dx = omp[2 * k + 1], m = omp[18 + k];
        float py = (float)h + (float)(k / 3 - 1) + dy;
        float px = (float)w + (float)(k % 3 - 1) + dx;
        float y0f = floorf(py), x0f = floorf(px);
        float ly = py - y0f, lx = px - x0f;
        int y0 = (int)y0f, x0 = (int)x0f;
        int y1 = y0 + 1,   x1 = x0 + 1;
        bool vy0 = (y0 >= 0) && (y0 < HH), vy1 = (y1 >= 0) && (y1 < HH);
        bool vx0 = (x0 >= 0) && (x0 < WW), vx1 = (x1 >= 0) && (x1 < WW);
        int yc0 = min(max(y0, 0), HH - 1), yc1 = min(max(y1, 0), HH - 1);
        int xc0 = min(max(x0, 0), WW - 1), xc1 = min(max(x1, 0), WW - 1);
        int rb = b * HH;
        pI[tid][0] = ((rb + yc0) * WW + xc0) * CH;
        pI[tid][1] = ((rb + yc0) * WW + xc1) * CH;
        pI[tid][2] = ((rb + yc1) * WW + xc0) * CH;
        pI[tid][3] = ((rb + yc1) * WW + xc1) * CH;
        pW[tid][0] = (1.f - ly) * (1.f - lx) * m * ((vy0 && vx0) ? 1.f : 0.f);
        pW[tid][1] = (1.f - ly) * lx         * m * ((vy0 && vx1) ? 1.f : 0.f);
        pW[tid][2] = ly         * (1.f - lx) * m * ((vy1 && vx0) ? 1.f : 0.f);
        pW[tid][3] = ly         * lx         * m * ((vy1 && vx1) ? 1.f : 0.f);
    }
    __syncthreads();

    // Phase B: build s[pix][c*9+k] = mask-weighted bilinear sample
    for (int v = tid; v < TP * KK * CH; v += 256) {
        int k    = v >> 11;          // v / 2048
        int r    = v & 2047;
        int pixl = r >> 7;
        int c    = r & 127;
        int pk   = pixl * KK + k;
        float sum = pW[pk][0] * x_t[pI[pk][0] + c]
                  + pW[pk][1] * x_t[pI[pk][1] + c]
                  + pW[pk][2] * x_t[pI[pk][2] + c]
                  + pW[pk][3] * x_t[pI[pk][3] + c];
        s[pixl * KDIM + c * KK + k] = sum;
    }
    __syncthreads();

    // Phase C: y[o, pix] = sum_j s[pix][j] * weight[o][j]  (2 o x 4 pix per thread)
    int o0 = (tid & 63) * 2;
    int pq = tid >> 6;              // 0..3 -> pixels pq*4 .. pq*4+3
    const float4* wa4 = (const float4*)(weight + (size_t)o0 * KDIM);
    const float4* wb4 = (const float4*)(weight + (size_t)(o0 + 1) * KDIM);
    const float4* s0 = (const float4*)(s + (pq * 4 + 0) * KDIM);
    const float4* s1 = (const float4*)(s + (pq * 4 + 1) * KDIM);
    const float4* s2 = (const float4*)(s + (pq * 4 + 2) * KDIM);
    const float4* s3 = (const float4*)(s + (pq * 4 + 3) * KDIM);

    float a00 = 0.f, a01 = 0.f, a02 = 0.f, a03 = 0.f;
    float a10 = 0.f, a11 = 0.f, a12 = 0.f, a13 = 0.f;
    for (int j = 0; j < KDIM / 4; j++) {
        float4 wa = wa4[j], wb = wb4[j];
        float4 v0 = s0[j], v1 = s1[j], v2 = s2[j], v3 = s3[j];
        a00 += wa.x * v0.x + wa.y * v0.y + wa.z * v0.z + wa.w * v0.w;
        a01 += wa.x * v1.x + wa.y * v1.y + wa.z * v1.z + wa.w * v1.w;
        a02 += wa.x * v2.x + wa.y * v2.y + wa.z * v2.z + wa.w * v2.w;
        a03 += wa.x * v3.x + wa.y * v3.y + wa.z * v3.z + wa.w * v3.w;
        a10 += wb.x * v0.x + wb.y * v0.y + wb.z * v0.z + wb.w * v0.w;
        a11 += wb.x * v1.x + wb.y * v1.y + wb.z * v1.z + wb.w * v1.w;
        a12 += wb.x * v2.x + wb.y * v2.y + wb.z * v2.z + wb.w * v2.w;
        a13 += wb.x * v3.x + wb.y * v3.y + wb.z * v3.z + wb.w * v3.w;
    }
    float b0 = bias[o0], b1 = bias[o0 + 1];
    float* outp0 = out + (size_t)(b * CH + o0) * HWSZ + h * WW + w0 + pq * 4;
    float* outp1 = outp0 + HWSZ;
    *(float4*)outp0 = make_float4(a00 + b0, a01 + b0, a02 + b0, a03 + b0);
    *(float4*)outp1 = make_float4(a10 + b1, a11 + b1, a12 + b1, a13 + b1);
}

extern "C" void kernel_launch(void* const* d_in, const int* in_sizes, int n_in,
                              void* d_out, int out_size, void* d_ws, size_t ws_size,
                              hipStream_t stream) {
    const float* x        = (const float*)d_in[0];
    const float* offset_w = (const float*)d_in[1];
    const float* offset_b = (const float*)d_in[2];
    const float* mask_w   = (const float*)d_in[3];
    const float* mask_b   = (const float*)d_in[4];
    const float* weight   = (const float*)d_in[5];
    const float* bias     = (const float*)d_in[6];
    float* out = (float*)d_out;

    float* x_t = (float*)d_ws;                       // 8*128*64*64 = 4,194,304 floats
    float* om  = x_t + (size_t)BATCH * CH * HWSZ;    // 32768*27    =   884,736 floats

    dim3 tb(32, 8, 1);
    dim3 tg(HWSZ / 32, CH / 32, BATCH);
    k_transpose<<<tg, tb, 0, stream>>>(x, x_t);

    int npix = BATCH * HWSZ;                         // 32768
    k_offmask2<<<npix / TP1, 256, 0, stream>>>(x_t, offset_w, offset_b, mask_w, mask_b, om);

    k_deform<<<npix / TP, 256, 0, stream>>>(x_t, om, weight, bias, out);
}

// Round 3
// 171.423 us; speedup vs baseline: 38.1801x; 3.8069x over previous
//
#include <hip/hip_runtime.h>
#include <math.h>

#define BATCH 8
#define CH    128
#define HH    64
#define WW    64
#define HWSZ  (HH*WW)        // 4096
#define KK    9
#define OC27  27
#define KDIM  1152           // CH*KK

typedef unsigned short ushort_t;
typedef unsigned int   uint_t;
typedef __attribute__((ext_vector_type(8))) short  short8v;
typedef __attribute__((ext_vector_type(4))) float  float4v;

__device__ __forceinline__ float bf2f(uint_t u16) {        // low 16 bits = bf16
    return __uint_as_float(u16 << 16);
}
__device__ __forceinline__ float bf2f_hi(uint_t u) {       // high half of packed pair
    return __uint_as_float(u & 0xffff0000u);
}
__device__ __forceinline__ ushort_t f2bf(float f) {        // RNE
    uint_t u = __float_as_uint(f);
    return (ushort_t)((u + 0x7fffu + ((u >> 16) & 1u)) >> 16);
}

// ---------------- K0: NCHW f32 -> NHWC bf16 ----------------
__global__ void k_prep_x(const float* __restrict__ in, ushort_t* __restrict__ out) {
    __shared__ float tile[32][33];
    int b  = blockIdx.z;
    int c0 = blockIdx.y * 32;
    int s0 = blockIdx.x * 32;
    int tx = threadIdx.x, ty = threadIdx.y;
    const float* inb = in  + (size_t)b * CH * HWSZ;
    ushort_t*   outb = out + (size_t)b * HWSZ * CH;
#pragma unroll
    for (int i = 0; i < 32; i += 8)
        tile[ty + i][tx] = inb[(size_t)(c0 + ty + i) * HWSZ + s0 + tx];
    __syncthreads();
#pragma unroll
    for (int i = 0; i < 32; i += 8)
        outb[(size_t)(s0 + ty + i) * CH + c0 + tx] = f2bf(tile[tx][ty + i]);
}

// ---------------- K0b: weight f32 -> bf16 in B-fragment layout ----------------
// k_lin = (c/32)*288 + t*32 + (c%32);  w2[k_lin/8][oc][k_lin%8]
__global__ __launch_bounds__(256) void k_prep_w(const float* __restrict__ weight,
                                                ushort_t* __restrict__ w2) {
    int e = blockIdx.x * 256 + threadIdx.x;          // e = oc*1152 + c*9 + t
    if (e >= CH * KDIM) return;
    int oc  = e / KDIM;
    int rem = e - oc * KDIM;
    int c   = rem / KK;
    int t   = rem - c * KK;
    int k_lin = (c >> 5) * 288 + t * 32 + (c & 31);
    w2[(size_t)(k_lin >> 3) * (CH * 8) + oc * 8 + (k_lin & 7)] = f2bf(weight[e]);
}

// ---------------- K1: offset+mask conv3x3 via LDS im2col tile ----------------
#define TP1 16
#define SROW 1156

__global__ __launch_bounds__(256) void k_offmask2(
        const ushort_t* __restrict__ x_bf,
        const float* __restrict__ offset_w, const float* __restrict__ offset_b,
        const float* __restrict__ mask_w,   const float* __restrict__ mask_b,
        float* __restrict__ om) {
    __shared__ float s[TP1][SROW];
    __shared__ int   base[TP1 * KK];
    __shared__ float vmul[TP1 * KK];

    int tid = threadIdx.x;
    int p0  = blockIdx.x * TP1;
    int b   = p0 >> 12;
    int h   = (p0 >> 6) & 63;
    int w0  = p0 & 63;

    if (tid < TP1 * KK) {
        int pixl = tid / KK, t = tid % KK;
        int w = w0 + pixl;
        int y = h + t / 3 - 1;
        int x = w + t % 3 - 1;
        bool v = (y >= 0) && (y < HH) && (x >= 0) && (x < WW);
        int yc = v ? y : 0, xc = v ? x : 0;
        base[tid] = ((b * HH + yc) * WW + xc) * CH;
        vmul[tid] = v ? 1.f : 0.f;
    }
    __syncthreads();

    // build im2col tile s[pix][c*9+t] (f32), 2 channels/thread
    for (int v = tid; v < TP1 * KK * (CH / 2); v += 256) {
        int t    = v >> 10;            // /(16*64)
        int r    = v & 1023;
        int pixl = r >> 6;
        int cp   = (r & 63) * 2;
        int pk   = pixl * KK + t;
        uint_t u = *(const uint_t*)(x_bf + base[pk] + cp);
        float m  = vmul[pk];
        s[pixl][cp * KK + t]       = m * bf2f(u & 0xffffu);
        s[pixl][(cp + 1) * KK + t] = m * bf2f_hi(u);
    }
    __syncthreads();

    if (tid < 216) {
        int oc = tid / 8;
        int pp = tid % 8;
        const float* wrow = (oc < 18) ? offset_w + (size_t)oc * KDIM
                                      : mask_w   + (size_t)(oc - 18) * KDIM;
        float bv = (oc < 18) ? offset_b[oc] : mask_b[oc - 18];
        const float4* w4 = (const float4*)wrow;
        const float4* sa = (const float4*)&s[2 * pp][0];
        const float4* sb = (const float4*)&s[2 * pp + 1][0];
        float a0 = 0.f, a1 = 0.f;
#pragma unroll 4
        for (int j = 0; j < KDIM / 4; j++) {
            float4 wv = w4[j], va = sa[j], vb = sb[j];
            a0 += wv.x * va.x + wv.y * va.y + wv.z * va.z + wv.w * va.w;
            a1 += wv.x * vb.x + wv.y * vb.y + wv.z * vb.z + wv.w * vb.w;
        }
        a0 += bv; a1 += bv;
        if (oc >= 18) {
            a0 = 1.f / (1.f + expf(-a0));
            a1 = 1.f / (1.f + expf(-a1));
        }
        om[(size_t)(p0 + 2 * pp)     * OC27 + oc] = a0;
        om[(size_t)(p0 + 2 * pp + 1) * OC27 + oc] = a1;
    }
}

// ---------------- K2: deformable gather + MFMA contraction ----------------
#define DP    64     // pixels per block (one full image row)
#define KC    288    // K per channel-chunk (32 ch * 9 taps)
#define RS    296    // padded LDS row stride in bf16 elems (592 B, 16B-mult)

__global__ __launch_bounds__(256) void k_deform_mfma(
        const ushort_t* __restrict__ x_bf,
        const float* __restrict__ om,
        const ushort_t* __restrict__ w2,
        const float* __restrict__ bias,
        float* __restrict__ out) {
    __shared__ ushort_t s[DP * RS];        // 37,888 B
    __shared__ int   pI[DP * KK][4];
    __shared__ float pW[DP * KK][4];

    int tid = threadIdx.x;
    int p0  = blockIdx.x * DP;
    int b   = p0 >> 12;
    int h   = (p0 >> 6) & 63;

    // Phase A: bilinear params per (pixel, tap)
    for (int v = tid; v < DP * KK; v += 256) {
        int pixl = v / KK;
        int k    = v - pixl * KK;
        const float* omp = om + (size_t)(p0 + pixl) * OC27;
        float dy = omp[2 * k], dx = omp[2 * k + 1], m = omp[18 + k];
        float py = (float)h    + (float)(k / 3 - 1) + dy;
        float px = (float)pixl + (float)(k % 3 - 1) + dx;
        float y0f = floorf(py), x0f = floorf(px);
        float ly = py - y0f, lx = px - x0f;
        int y0 = (int)y0f, x0 = (int)x0f;
        int y1 = y0 + 1,   x1 = x0 + 1;
        bool vy0 = (y0 >= 0) && (y0 < HH), vy1 = (y1 >= 0) && (y1 < HH);
        bool vx0 = (x0 >= 0) && (x0 < WW), vx1 = (x1 >= 0) && (x1 < WW);
        int yc0 = min(max(y0, 0), HH - 1), yc1 = min(max(y1, 0), HH - 1);
        int xc0 = min(max(x0, 0), WW - 1), xc1 = min(max(x1, 0), WW - 1);
        int rb = b * HH;
        pI[v][0] = ((rb + yc0) * WW + xc0) * CH;
        pI[v][1] = ((rb + yc0) * WW + xc1) * CH;
        pI[v][2] = ((rb + yc1) * WW + xc0) * CH;
        pI[v][3] = ((rb + yc1) * WW + xc1) * CH;
        pW[v][0] = (1.f - ly) * (1.f - lx) * m * ((vy0 && vx0) ? 1.f : 0.f);
        pW[v][1] = (1.f - ly) * lx         * m * ((vy0 && vx1) ? 1.f : 0.f);
        pW[v][2] = ly         * (1.f - lx) * m * ((vy1 && vx0) ? 1.f : 0.f);
        pW[v][3] = ly         * lx         * m * ((vy1 && vx1) ? 1.f : 0.f);
    }
    __syncthreads();

    int wid  = tid >> 6, lane = tid & 63;
    int wr   = wid & 1;          // pixel half (0/1 -> pix 0..31 / 32..63)
    int wc   = wid >> 1;         // oc half (0/1 -> oc 0..63 / 64..127)
    int lh   = lane >> 4;        // 0..3
    int ll   = lane & 15;        // 0..15

    float4v acc[2][4];
#pragma unroll
    for (int i = 0; i < 2; i++)
#pragma unroll
        for (int j = 0; j < 4; j++)
            acc[i][j] = (float4v){0.f, 0.f, 0.f, 0.f};

    for (int chunk = 0; chunk < 4; ++chunk) {
        int c0 = chunk * 32;
        // Phase B: gather bf16 A-tile, K-order = t*32 + (c-c0), 2 ch/thread
        for (int v = tid; v < DP * KK * 16; v += 256) {
            int t   = v >> 10;            // /(64*16)
            int r   = v & 1023;
            int pix = r >> 4;
            int cp  = (r & 15) * 2;
            int pk  = pix * KK + t;
            const int*   pIc = pI[pk];
            const float* pWc = pW[pk];
            int cb = c0 + cp;
            uint_t u0 = *(const uint_t*)(x_bf + pIc[0] + cb);
            uint_t u1 = *(const uint_t*)(x_bf + pIc[1] + cb);
            uint_t u2 = *(const uint_t*)(x_bf + pIc[2] + cb);
            uint_t u3 = *(const uint_t*)(x_bf + pIc[3] + cb);
            float w0f = pWc[0], w1f = pWc[1], w2f = pWc[2], w3f = pWc[3];
            float sLo = w0f * bf2f(u0 & 0xffffu);
            sLo = fmaf(w1f, bf2f(u1 & 0xffffu), sLo);
            sLo = fmaf(w2f, bf2f(u2 & 0xffffu), sLo);
            sLo = fmaf(w3f, bf2f(u3 & 0xffffu), sLo);
            float sHi = w0f * bf2f_hi(u0);
            sHi = fmaf(w1f, bf2f_hi(u1), sHi);
            sHi = fmaf(w2f, bf2f_hi(u2), sHi);
            sHi = fmaf(w3f, bf2f_hi(u3), sHi);
            uint_t pk2 = (uint_t)f2bf(sLo) | ((uint_t)f2bf(sHi) << 16);
            *(uint_t*)(&s[pix * RS + t * 32 + cp]) = pk2;
        }
        __syncthreads();

        // Phase C: 9 K-steps x 8 MFMA
        const ushort_t* wbase = w2 + (size_t)chunk * 36 * (CH * 8);
#pragma unroll 3
        for (int ks = 0; ks < 9; ++ks) {
            int k0 = ks * 32;
            short8v a0 = *(const short8v*)(&s[(wr * 32 + ll) * RS + k0 + lh * 8]);
            short8v a1 = *(const short8v*)(&s[(wr * 32 + 16 + ll) * RS + k0 + lh * 8]);
            const ushort_t* wp = wbase + (size_t)(ks * 4 + lh) * (CH * 8) + (wc * 64 + ll) * 8;
            short8v b0 = *(const short8v*)(wp);
            short8v b1 = *(const short8v*)(wp + 16 * 8);
            short8v b2 = *(const short8v*)(wp + 32 * 8);
            short8v b3 = *(const short8v*)(wp + 48 * 8);
            acc[0][0] = __builtin_amdgcn_mfma_f32_16x16x32_bf16(a0, b0, acc[0][0], 0, 0, 0);
            acc[0][1] = __builtin_amdgcn_mfma_f32_16x16x32_bf16(a0, b1, acc[0][1], 0, 0, 0);
            acc[0][2] = __builtin_amdgcn_mfma_f32_16x16x32_bf16(a0, b2, acc[0][2], 0, 0, 0);
            acc[0][3] = __builtin_amdgcn_mfma_f32_16x16x32_bf16(a0, b3, acc[0][3], 0, 0, 0);
            acc[1][0] = __builtin_amdgcn_mfma_f32_16x16x32_bf16(a1, b0, acc[1][0], 0, 0, 0);
            acc[1][1] = __builtin_amdgcn_mfma_f32_16x16x32_bf16(a1, b1, acc[1][1], 0, 0, 0);
            acc[1][2] = __builtin_amdgcn_mfma_f32_16x16x32_bf16(a1, b2, acc[1][2], 0, 0, 0);
            acc[1][3] = __builtin_amdgcn_mfma_f32_16x16x32_bf16(a1, b3, acc[1][3], 0, 0, 0);
        }
        __syncthreads();
    }

    // Epilogue: D col(oc)=ll, row(pix)=lh*4+reg
#pragma unroll
    for (int pi = 0; pi < 2; ++pi) {
#pragma unroll
        for (int oj = 0; oj < 4; ++oj) {
            int oc = wc * 64 + oj * 16 + ll;
            int w  = wr * 32 + pi * 16 + lh * 4;
            float bv = bias[oc];
            float4v a = acc[pi][oj];
            float* op = out + (((size_t)(b * CH + oc)) << 12) + (h << 6) + w;
            *(float4*)op = make_float4(a[0] + bv, a[1] + bv, a[2] + bv, a[3] + bv);
        }
    }
}

extern "C" void kernel_launch(void* const* d_in, const int* in_sizes, int n_in,
                              void* d_out, int out_size, void* d_ws, size_t ws_size,
                              hipStream_t stream) {
    const float* x        = (const float*)d_in[0];
    const float* offset_w = (const float*)d_in[1];
    const float* offset_b = (const float*)d_in[2];
    const float* mask_w   = (const float*)d_in[3];
    const float* mask_b   = (const float*)d_in[4];
    const float* weight   = (const float*)d_in[5];
    const float* bias     = (const float*)d_in[6];
    float* out = (float*)d_out;

    char* ws = (char*)d_ws;
    ushort_t* x_bf = (ushort_t*)ws;                            // 8,388,608 B
    float*    om   = (float*)(ws + 8388608);                   // 3,538,944 B
    ushort_t* w2   = (ushort_t*)(ws + 8388608 + 3538944);      //   294,912 B

    dim3 tb(32, 8, 1);
    dim3 tg(HWSZ / 32, CH / 32, BATCH);
    k_prep_x<<<tg, tb, 0, stream>>>(x, x_bf);

    k_prep_w<<<(CH * KDIM + 255) / 256, 256, 0, stream>>>(weight, w2);

    int npix = BATCH * HWSZ;                                   // 32768
    k_offmask2<<<npix / TP1, 256, 0, stream>>>(x_bf, offset_w, offset_b, mask_w, mask_b, om);

    k_deform_mfma<<<npix / DP, 256, 0, stream>>>(x_bf, om, w2, bias, out);
}

// Round 4
// 105.749 us; speedup vs baseline: 61.8916x; 1.6210x over previous
//
#include <hip/hip_runtime.h>
#include <math.h>

#define BATCH 8
#define CH    128
#define HH    64
#define WW    64
#define HWSZ  (HH*WW)        // 4096
#define KK    9
#define OC27  27
#define KDIM  1152           // CH*KK

typedef unsigned short ushort_t;
typedef unsigned int   uint_t;
typedef __attribute__((ext_vector_type(8))) short  short8v;
typedef __attribute__((ext_vector_type(4))) float  float4v;

__device__ __forceinline__ float bf2f(uint_t u16) {        // low 16 bits = bf16
    return __uint_as_float(u16 << 16);
}
__device__ __forceinline__ float bf2f_hi(uint_t u) {       // high half of packed pair
    return __uint_as_float(u & 0xffff0000u);
}
__device__ __forceinline__ ushort_t f2bf(float f) {        // RNE
    uint_t u = __float_as_uint(f);
    return (ushort_t)((u + 0x7fffu + ((u >> 16) & 1u)) >> 16);
}

// ---------------- K0: NCHW f32 -> NHWC bf16 ----------------
__global__ void k_prep_x(const float* __restrict__ in, ushort_t* __restrict__ out) {
    __shared__ float tile[32][33];
    int b  = blockIdx.z;
    int c0 = blockIdx.y * 32;
    int s0 = blockIdx.x * 32;
    int tx = threadIdx.x, ty = threadIdx.y;
    const float* inb = in  + (size_t)b * CH * HWSZ;
    ushort_t*   outb = out + (size_t)b * HWSZ * CH;
#pragma unroll
    for (int i = 0; i < 32; i += 8)
        tile[ty + i][tx] = inb[(size_t)(c0 + ty + i) * HWSZ + s0 + tx];
    __syncthreads();
#pragma unroll
    for (int i = 0; i < 32; i += 8)
        outb[(size_t)(s0 + ty + i) * CH + c0 + tx] = f2bf(tile[tx][ty + i]);
}

// ---------------- K0b: main weight f32 -> bf16 B-fragment layout ----------------
// k_lin = (c/32)*288 + t*32 + (c%32);  w2[k_lin/8][oc(128)][k_lin%8]
__global__ __launch_bounds__(256) void k_prep_w(const float* __restrict__ weight,
                                                ushort_t* __restrict__ w2) {
    int e = blockIdx.x * 256 + threadIdx.x;          // e = oc*1152 + c*9 + t
    if (e >= CH * KDIM) return;
    int oc  = e / KDIM;
    int rem = e - oc * KDIM;
    int c   = rem / KK;
    int t   = rem - c * KK;
    int k_lin = (c >> 5) * 288 + t * 32 + (c & 31);
    w2[(size_t)(k_lin >> 3) * (CH * 8) + oc * 8 + (k_lin & 7)] = f2bf(weight[e]);
}

// ---------------- K0c: offset+mask weights -> 32-col bf16 B panel ----------------
// oc 0..17 = offset_w rows, 18..26 = mask_w rows, 27..31 = zeros
__global__ __launch_bounds__(256) void k_prep_w_om(const float* __restrict__ offset_w,
                                                   const float* __restrict__ mask_w,
                                                   ushort_t* __restrict__ w2om) {
    int e = blockIdx.x * 256 + threadIdx.x;          // e = oc*1152 + c*9 + t
    if (e >= 32 * KDIM) return;
    int oc  = e / KDIM;
    int rem = e - oc * KDIM;
    int c   = rem / KK;
    int t   = rem - c * KK;
    float v = 0.f;
    if (oc < 18)      v = offset_w[(size_t)oc * KDIM + rem];
    else if (oc < 27) v = mask_w[(size_t)(oc - 18) * KDIM + rem];
    int k_lin = (c >> 5) * 288 + t * 32 + (c & 31);
    w2om[(size_t)(k_lin >> 3) * (32 * 8) + oc * 8 + (k_lin & 7)] = f2bf(v);
}

#define DP    64     // pixels per block (one full image row)
#define RS    296    // padded LDS row stride in bf16 elems (592 B)

// ---------------- K1: offset+mask conv3x3 via MFMA ----------------
__global__ __launch_bounds__(256) void k_offmask_mfma(
        const ushort_t* __restrict__ x_bf,
        const ushort_t* __restrict__ w2om,
        const float* __restrict__ offset_b, const float* __restrict__ mask_b,
        float* __restrict__ om) {
    __shared__ ushort_t s[DP * RS];        // 37,888 B

    int tid = threadIdx.x;
    int p0  = blockIdx.x * DP;
    int b   = p0 >> 12;
    int h   = (p0 >> 6) & 63;
    int wid = tid >> 6, lane = tid & 63;
    int lh  = lane >> 4, ll = lane & 15;

    float4v acc[2];
    acc[0] = (float4v){0.f, 0.f, 0.f, 0.f};
    acc[1] = (float4v){0.f, 0.f, 0.f, 0.f};

    for (int chunk = 0; chunk < 4; ++chunk) {
        int c0 = chunk * 32;
        // Phase B: regular im2col A-tile (zero-padded borders)
        for (int v = tid; v < DP * KK * 16; v += 256) {
            int t   = v >> 10;            // /(64*16)
            int r   = v & 1023;
            int pix = r >> 4;
            int cp  = (r & 15) * 2;
            int y   = h + t / 3 - 1;
            int x   = pix + t % 3 - 1;
            bool valid = (y >= 0) && (y < HH) && (x >= 0) && (x < WW);
            uint_t u = 0;
            if (valid)
                u = *(const uint_t*)(x_bf + ((size_t)((b * HH + y) * WW + x) * CH) + c0 + cp);
            *(uint_t*)(&s[pix * RS + t * 32 + cp]) = u;
        }
        __syncthreads();

        const ushort_t* wb = w2om + (size_t)chunk * 36 * (32 * 8);
#pragma unroll 3
        for (int ks = 0; ks < 9; ++ks) {
            short8v a = *(const short8v*)(&s[(wid * 16 + ll) * RS + ks * 32 + lh * 8]);
            const ushort_t* wp = wb + (size_t)(ks * 4 + lh) * (32 * 8) + ll * 8;
            short8v b0 = *(const short8v*)(wp);
            short8v b1 = *(const short8v*)(wp + 16 * 8);
            acc[0] = __builtin_amdgcn_mfma_f32_16x16x32_bf16(a, b0, acc[0], 0, 0, 0);
            acc[1] = __builtin_amdgcn_mfma_f32_16x16x32_bf16(a, b1, acc[1], 0, 0, 0);
        }
        __syncthreads();
    }

    // Epilogue: col(oc)=ll per tile, row(pix within wave)=lh*4+reg
#pragma unroll
    for (int j = 0; j < 2; ++j) {
        int oc = j * 16 + ll;
        if (oc < OC27) {
            float bv = (oc < 18) ? offset_b[oc] : mask_b[oc - 18];
            bool sig = (oc >= 18);
#pragma unroll
            for (int r = 0; r < 4; ++r) {
                int pix = wid * 16 + lh * 4 + r;
                float vv = acc[j][r] + bv;
                if (sig) vv = 1.f / (1.f + expf(-vv));
                om[(size_t)(p0 + pix) * OC27 + oc] = vv;
            }
        }
    }
}

// ---------------- K2: deformable gather + MFMA contraction ----------------
__global__ __launch_bounds__(256) void k_deform_mfma(
        const ushort_t* __restrict__ x_bf,
        const float* __restrict__ om,
        const ushort_t* __restrict__ w2,
        const float* __restrict__ bias,
        float* __restrict__ out) {
    __shared__ ushort_t s[DP * RS];        // 37,888 B
    __shared__ int   pI[DP * KK][4];
    __shared__ float pW[DP * KK][4];

    int tid = threadIdx.x;
    int p0  = blockIdx.x * DP;
    int b   = p0 >> 12;
    int h   = (p0 >> 6) & 63;

    // Phase A: bilinear params per (pixel, tap)
    for (int v = tid; v < DP * KK; v += 256) {
        int pixl = v / KK;
        int k    = v - pixl * KK;
        const float* omp = om + (size_t)(p0 + pixl) * OC27;
        float dy = omp[2 * k], dx = omp[2 * k + 1], m = omp[18 + k];
        float py = (float)h    + (float)(k / 3 - 1) + dy;
        float px = (float)pixl + (float)(k % 3 - 1) + dx;
        float y0f = floorf(py), x0f = floorf(px);
        float ly = py - y0f, lx = px - x0f;
        int y0 = (int)y0f, x0 = (int)x0f;
        int y1 = y0 + 1,   x1 = x0 + 1;
        bool vy0 = (y0 >= 0) && (y0 < HH), vy1 = (y1 >= 0) && (y1 < HH);
        bool vx0 = (x0 >= 0) && (x0 < WW), vx1 = (x1 >= 0) && (x1 < WW);
        int yc0 = min(max(y0, 0), HH - 1), yc1 = min(max(y1, 0), HH - 1);
        int xc0 = min(max(x0, 0), WW - 1), xc1 = min(max(x1, 0), WW - 1);
        int rb = b * HH;
        pI[v][0] = ((rb + yc0) * WW + xc0) * CH;
        pI[v][1] = ((rb + yc0) * WW + xc1) * CH;
        pI[v][2] = ((rb + yc1) * WW + xc0) * CH;
        pI[v][3] = ((rb + yc1) * WW + xc1) * CH;
        pW[v][0] = (1.f - ly) * (1.f - lx) * m * ((vy0 && vx0) ? 1.f : 0.f);
        pW[v][1] = (1.f - ly) * lx         * m * ((vy0 && vx1) ? 1.f : 0.f);
        pW[v][2] = ly         * (1.f - lx) * m * ((vy1 && vx0) ? 1.f : 0.f);
        pW[v][3] = ly         * lx         * m * ((vy1 && vx1) ? 1.f : 0.f);
    }
    __syncthreads();

    int wid  = tid >> 6, lane = tid & 63;
    int wr   = wid & 1;          // pixel half
    int wc   = wid >> 1;         // oc half
    int lh   = lane >> 4;
    int ll   = lane & 15;

    float4v acc[2][4];
#pragma unroll
    for (int i = 0; i < 2; i++)
#pragma unroll
        for (int j = 0; j < 4; j++)
            acc[i][j] = (float4v){0.f, 0.f, 0.f, 0.f};

    for (int chunk = 0; chunk < 4; ++chunk) {
        int c0 = chunk * 32;
        // Phase B: gather bf16 A-tile, K-order = t*32 + (c-c0), 2 ch/thread
        for (int v = tid; v < DP * KK * 16; v += 256) {
            int t   = v >> 10;
            int r   = v & 1023;
            int pix = r >> 4;
            int cp  = (r & 15) * 2;
            int pk  = pix * KK + t;
            const int*   pIc = pI[pk];
            const float* pWc = pW[pk];
            int cb = c0 + cp;
            uint_t u0 = *(const uint_t*)(x_bf + pIc[0] + cb);
            uint_t u1 = *(const uint_t*)(x_bf + pIc[1] + cb);
            uint_t u2 = *(const uint_t*)(x_bf + pIc[2] + cb);
            uint_t u3 = *(const uint_t*)(x_bf + pIc[3] + cb);
            float w0f = pWc[0], w1f = pWc[1], w2f = pWc[2], w3f = pWc[3];
            float sLo = w0f * bf2f(u0 & 0xffffu);
            sLo = fmaf(w1f, bf2f(u1 & 0xffffu), sLo);
            sLo = fmaf(w2f, bf2f(u2 & 0xffffu), sLo);
            sLo = fmaf(w3f, bf2f(u3 & 0xffffu), sLo);
            float sHi = w0f * bf2f_hi(u0);
            sHi = fmaf(w1f, bf2f_hi(u1), sHi);
            sHi = fmaf(w2f, bf2f_hi(u2), sHi);
            sHi = fmaf(w3f, bf2f_hi(u3), sHi);
            uint_t pk2 = (uint_t)f2bf(sLo) | ((uint_t)f2bf(sHi) << 16);
            *(uint_t*)(&s[pix * RS + t * 32 + cp]) = pk2;
        }
        __syncthreads();

        // Phase C: 9 K-steps x 8 MFMA
        const ushort_t* wbase = w2 + (size_t)chunk * 36 * (CH * 8);
#pragma unroll 3
        for (int ks = 0; ks < 9; ++ks) {
            int k0 = ks * 32;
            short8v a0 = *(const short8v*)(&s[(wr * 32 + ll) * RS + k0 + lh * 8]);
            short8v a1 = *(const short8v*)(&s[(wr * 32 + 16 + ll) * RS + k0 + lh * 8]);
            const ushort_t* wp = w2 + (size_t)chunk * 36 * (CH * 8)
                               + (size_t)(ks * 4 + lh) * (CH * 8) + (wc * 64 + ll) * 8;
            short8v b0 = *(const short8v*)(wp);
            short8v b1 = *(const short8v*)(wp + 16 * 8);
            short8v b2 = *(const short8v*)(wp + 32 * 8);
            short8v b3 = *(const short8v*)(wp + 48 * 8);
            acc[0][0] = __builtin_amdgcn_mfma_f32_16x16x32_bf16(a0, b0, acc[0][0], 0, 0, 0);
            acc[0][1] = __builtin_amdgcn_mfma_f32_16x16x32_bf16(a0, b1, acc[0][1], 0, 0, 0);
            acc[0][2] = __builtin_amdgcn_mfma_f32_16x16x32_bf16(a0, b2, acc[0][2], 0, 0, 0);
            acc[0][3] = __builtin_amdgcn_mfma_f32_16x16x32_bf16(a0, b3, acc[0][3], 0, 0, 0);
            acc[1][0] = __builtin_amdgcn_mfma_f32_16x16x32_bf16(a1, b0, acc[1][0], 0, 0, 0);
            acc[1][1] = __builtin_amdgcn_mfma_f32_16x16x32_bf16(a1, b1, acc[1][1], 0, 0, 0);
            acc[1][2] = __builtin_amdgcn_mfma_f32_16x16x32_bf16(a1, b2, acc[1][2], 0, 0, 0);
            acc[1][3] = __builtin_amdgcn_mfma_f32_16x16x32_bf16(a1, b3, acc[1][3], 0, 0, 0);
        }
        __syncthreads();
    }

    // Epilogue: D col(oc)=ll, row(pix)=lh*4+reg
#pragma unroll
    for (int pi = 0; pi < 2; ++pi) {
#pragma unroll
        for (int oj = 0; oj < 4; ++oj) {
            int oc = wc * 64 + oj * 16 + ll;
            int w  = wr * 32 + pi * 16 + lh * 4;
            float bv = bias[oc];
            float4v a = acc[pi][oj];
            float* op = out + (((size_t)(b * CH + oc)) << 12) + (h << 6) + w;
            *(float4*)op = make_float4(a[0] + bv, a[1] + bv, a[2] + bv, a[3] + bv);
        }
    }
}

extern "C" void kernel_launch(void* const* d_in, const int* in_sizes, int n_in,
                              void* d_out, int out_size, void* d_ws, size_t ws_size,
                              hipStream_t stream) {
    const float* x        = (const float*)d_in[0];
    const float* offset_w = (const float*)d_in[1];
    const float* offset_b = (const float*)d_in[2];
    const float* mask_w   = (const float*)d_in[3];
    const float* mask_b   = (const float*)d_in[4];
    const float* weight   = (const float*)d_in[5];
    const float* bias     = (const float*)d_in[6];
    float* out = (float*)d_out;

    char* ws = (char*)d_ws;
    ushort_t* x_bf = (ushort_t*)ws;                            // 8,388,608 B
    float*    om   = (float*)(ws + 8388608);                   // 3,538,944 B
    ushort_t* w2   = (ushort_t*)(ws + 8388608 + 3538944);      //   294,912 B
    ushort_t* w2om = (ushort_t*)(ws + 8388608 + 3538944 + 294912); // 73,728 B

    dim3 tb(32, 8, 1);
    dim3 tg(HWSZ / 32, CH / 32, BATCH);
    k_prep_x<<<tg, tb, 0, stream>>>(x, x_bf);

    k_prep_w<<<(CH * KDIM + 255) / 256, 256, 0, stream>>>(weight, w2);
    k_prep_w_om<<<(32 * KDIM + 255) / 256, 256, 0, stream>>>(offset_w, mask_w, w2om);

    int npix = BATCH * HWSZ;                                   // 32768
    k_offmask_mfma<<<npix / DP, 256, 0, stream>>>(x_bf, w2om, offset_b, mask_b, om);

    k_deform_mfma<<<npix / DP, 256, 0, stream>>>(x_bf, om, w2, bias, out);
}

// Round 5
// 61.971 us; speedup vs baseline: 105.6125x; 1.7064x over previous
//
#include <hip/hip_runtime.h>
#include <math.h>

#define BATCH 8
#define CH    128
#define HH    64
#define WW    64
#define HWSZ  (HH*WW)        // 4096
#define KK    9
#define OC27  27
#define KDIM  1152           // CH*KK

typedef unsigned short ushort_t;
typedef unsigned int   uint_t;
typedef __attribute__((ext_vector_type(8))) short  short8v;
typedef __attribute__((ext_vector_type(4))) float  float4v;

__device__ __forceinline__ float bf2f(uint_t u16) {        // low 16 bits = bf16
    return __uint_as_float(u16 << 16);
}
__device__ __forceinline__ float bf2f_hi(uint_t u) {       // high half of packed pair
    return __uint_as_float(u & 0xffff0000u);
}
__device__ __forceinline__ ushort_t f2bf(float f) {        // RNE
    uint_t u = __float_as_uint(f);
    return (ushort_t)((u + 0x7fffu + ((u >> 16) & 1u)) >> 16);
}

// ---------------- K0: NCHW f32 -> NHWC bf16 ----------------
__global__ void k_prep_x(const float* __restrict__ in, ushort_t* __restrict__ out) {
    __shared__ float tile[32][33];
    int b  = blockIdx.z;
    int c0 = blockIdx.y * 32;
    int s0 = blockIdx.x * 32;
    int tx = threadIdx.x, ty = threadIdx.y;
    const float* inb = in  + (size_t)b * CH * HWSZ;
    ushort_t*   outb = out + (size_t)b * HWSZ * CH;
#pragma unroll
    for (int i = 0; i < 32; i += 8)
        tile[ty + i][tx] = inb[(size_t)(c0 + ty + i) * HWSZ + s0 + tx];
    __syncthreads();
#pragma unroll
    for (int i = 0; i < 32; i += 8)
        outb[(size_t)(s0 + ty + i) * CH + c0 + tx] = f2bf(tile[tx][ty + i]);
}

// ---------------- K0b: main weight f32 -> bf16 B-fragment layout ----------------
// k_lin = (c/32)*288 + t*32 + (c%32);  w2[k_lin/8][oc(128)][k_lin%8]
__global__ __launch_bounds__(256) void k_prep_w(const float* __restrict__ weight,
                                                ushort_t* __restrict__ w2) {
    int e = blockIdx.x * 256 + threadIdx.x;          // e = oc*1152 + c*9 + t
    if (e >= CH * KDIM) return;
    int oc  = e / KDIM;
    int rem = e - oc * KDIM;
    int c   = rem / KK;
    int t   = rem - c * KK;
    int k_lin = (c >> 5) * 288 + t * 32 + (c & 31);
    w2[(size_t)(k_lin >> 3) * (CH * 8) + oc * 8 + (k_lin & 7)] = f2bf(weight[e]);
}

// ---------------- K0c: offset+mask weights -> 32-col bf16 B panel ----------------
__global__ __launch_bounds__(256) void k_prep_w_om(const float* __restrict__ offset_w,
                                                   const float* __restrict__ mask_w,
                                                   ushort_t* __restrict__ w2om) {
    int e = blockIdx.x * 256 + threadIdx.x;          // e = oc*1152 + c*9 + t
    if (e >= 32 * KDIM) return;
    int oc  = e / KDIM;
    int rem = e - oc * KDIM;
    int c   = rem / KK;
    int t   = rem - c * KK;
    float v = 0.f;
    if (oc < 18)      v = offset_w[(size_t)oc * KDIM + rem];
    else if (oc < 27) v = mask_w[(size_t)(oc - 18) * KDIM + rem];
    int k_lin = (c >> 5) * 288 + t * 32 + (c & 31);
    w2om[(size_t)(k_lin >> 3) * (32 * 8) + oc * 8 + (k_lin & 7)] = f2bf(v);
}

// ---------------- Fused: offmask conv + params + deform gather + main GEMM ----------------
#define DP   64      // pixels per block (one full image row)
#define RSE  320     // LDS row stride in bf16 elems (640 B); 288 used, XOR swizzle safe

// element-index swizzle: off ^= (row&7)<<3  (flips elem bits 3-5, stays 16B-aligned)
__device__ __forceinline__ int swz(int row, int off) { return off ^ ((row & 7) << 3); }

__global__ __launch_bounds__(256) void k_fused(
        const ushort_t* __restrict__ x_bf,
        const ushort_t* __restrict__ w2,
        const ushort_t* __restrict__ w2om,
        const float* __restrict__ offset_b, const float* __restrict__ mask_b,
        const float* __restrict__ bias,
        float* __restrict__ out) {
    __shared__ ushort_t s[DP * RSE];       // 40,960 B
    __shared__ float    psf[2880];         // 11,520 B: om[64][27] -> wq[576][4] + enc[576]

    int tid = threadIdx.x;
    int p0  = blockIdx.x * DP;
    int b   = p0 >> 12;
    int h   = (p0 >> 6) & 63;
    int wid = tid >> 6, lane = tid & 63;
    int lh  = lane >> 4, ll = lane & 15;

    const ushort_t* xb_img = x_bf + ((size_t)b * HWSZ * CH);

    // ============ Phase 1: offset/mask conv via MFMA ============
    float4v acc1[2];
    acc1[0] = (float4v){0.f, 0.f, 0.f, 0.f};
    acc1[1] = (float4v){0.f, 0.f, 0.f, 0.f};

    for (int chunk = 0; chunk < 4; ++chunk) {
        int c0 = chunk * 32;
#pragma unroll
        for (int i = 0; i < 9; ++i) {
            int v   = tid + i * 256;
            int t   = v >> 8;
            int r   = v & 255;
            int pix = r >> 2, cg = r & 3;
            int y   = h + t / 3 - 1;
            int x   = pix + t % 3 - 1;
            uint4 u = make_uint4(0u, 0u, 0u, 0u);
            if (y >= 0 && y < HH && x >= 0 && x < WW)
                u = *(const uint4*)(xb_img + (size_t)(y * WW + x) * CH + c0 + cg * 8);
            *(uint4*)(&s[pix * RSE + swz(pix, t * 32 + cg * 8)]) = u;
        }
        __syncthreads();

        const ushort_t* wb = w2om + (size_t)chunk * 36 * 256;
#pragma unroll 3
        for (int ks = 0; ks < 9; ++ks) {
            int row = wid * 16 + ll;
            short8v a = *(const short8v*)(&s[row * RSE + swz(row, ks * 32 + lh * 8)]);
            const ushort_t* wp = wb + (ks * 4 + lh) * 256 + ll * 8;
            short8v b0 = *(const short8v*)(wp);
            short8v b1 = *(const short8v*)(wp + 128);
            acc1[0] = __builtin_amdgcn_mfma_f32_16x16x32_bf16(a, b0, acc1[0], 0, 0, 0);
            acc1[1] = __builtin_amdgcn_mfma_f32_16x16x32_bf16(a, b1, acc1[1], 0, 0, 0);
        }
        __syncthreads();
    }

    // epilogue -> om in psf[pix*27 + oc]
#pragma unroll
    for (int j = 0; j < 2; ++j) {
        int oc = j * 16 + ll;
        if (oc < OC27) {
            float bv = (oc < 18) ? offset_b[oc] : mask_b[oc - 18];
#pragma unroll
            for (int r = 0; r < 4; ++r) {
                int pix = wid * 16 + lh * 4 + r;
                float vv = acc1[j][r] + bv;
                if (oc >= 18) vv = 1.f / (1.f + expf(-vv));
                psf[pix * 27 + oc] = vv;
            }
        }
    }
    __syncthreads();

    // ============ Phase A: bilinear params (compact) ============
    // items v = tid, tid+256, (tid<64: tid+512);  v -> (pix = v/9, t = v%9)
    float dy0 = 0.f, dx0 = 0.f, m0 = 0.f, dy1 = 0.f, dx1 = 0.f, m1 = 0.f;
    float dy2 = 0.f, dx2 = 0.f, m2 = 0.f;
    {
        int v0 = tid,      pA = v0 / 9, tA = v0 - pA * 9;
        int v1 = tid + 256, pB = v1 / 9, tB = v1 - pB * 9;
        dy0 = psf[pA * 27 + 2 * tA]; dx0 = psf[pA * 27 + 2 * tA + 1]; m0 = psf[pA * 27 + 18 + tA];
        dy1 = psf[pB * 27 + 2 * tB]; dx1 = psf[pB * 27 + 2 * tB + 1]; m1 = psf[pB * 27 + 18 + tB];
        if (tid < 64) {
            int v2 = tid + 512, pC = v2 / 9, tC = v2 - pC * 9;
            dy2 = psf[pC * 27 + 2 * tC]; dx2 = psf[pC * 27 + 2 * tC + 1]; m2 = psf[pC * 27 + 18 + tC];
        }
    }
    __syncthreads();

    uint_t* enc = (uint_t*)(psf + 2304);
#define PARAM_STORE(v, dy, dx, m) {                                             \
        int pix = (v) / 9, t = (v) - pix * 9;                                   \
        float py = (float)(h + t / 3 - 1) + (dy);                               \
        float px = (float)(pix + t % 3 - 1) + (dx);                             \
        float y0f = floorf(py), x0f = floorf(px);                               \
        float ly = py - y0f, lx = px - x0f;                                     \
        int y0 = (int)y0f, x0 = (int)x0f;                                       \
        int y1 = y0 + 1,   x1 = x0 + 1;                                         \
        bool vy0 = (y0 >= 0) & (y0 < HH), vy1 = (y1 >= 0) & (y1 < HH);          \
        bool vx0 = (x0 >= 0) & (x0 < WW), vx1 = (x1 >= 0) & (x1 < WW);          \
        int yc0 = min(max(y0, 0), HH - 1), yc1 = min(max(y1, 0), HH - 1);       \
        int xc0 = min(max(x0, 0), WW - 1), xc1 = min(max(x1, 0), WW - 1);       \
        int idx00 = (yc0 * WW + xc0) * CH;                                      \
        enc[v] = (uint_t)idx00 | ((uint_t)(xc1 - xc0) << 30)                    \
                               | ((uint_t)(yc1 - yc0) << 31);                   \
        float4 wq;                                                              \
        wq.x = (1.f - ly) * (1.f - lx) * (m) * ((vy0 && vx0) ? 1.f : 0.f);      \
        wq.y = (1.f - ly) * lx         * (m) * ((vy0 && vx1) ? 1.f : 0.f);      \
        wq.z = ly         * (1.f - lx) * (m) * ((vy1 && vx0) ? 1.f : 0.f);      \
        wq.w = ly         * lx         * (m) * ((vy1 && vx1) ? 1.f : 0.f);      \
        *(float4*)(&psf[(v) * 4]) = wq;                                         \
    }
    PARAM_STORE(tid,       dy0, dx0, m0);
    PARAM_STORE(tid + 256, dy1, dx1, m1);
    if (tid < 64) PARAM_STORE(tid + 512, dy2, dx2, m2);
#undef PARAM_STORE
    __syncthreads();

    // ============ Phase 2: deformed gather + main MFMA ============
    int wr = wid & 1;            // pixel half
    int wc = wid >> 1;           // oc half
    float4v acc[2][4];
#pragma unroll
    for (int i = 0; i < 2; i++)
#pragma unroll
        for (int j = 0; j < 4; j++)
            acc[i][j] = (float4v){0.f, 0.f, 0.f, 0.f};

    for (int chunk = 0; chunk < 4; ++chunk) {
        int c0 = chunk * 32;
#pragma unroll
        for (int i = 0; i < 9; ++i) {
            int v   = tid + i * 256;
            int t   = v >> 8;
            int r   = v & 255;
            int pix = r >> 2, cg = r & 3;
            int pv  = pix * 9 + t;
            uint_t e  = enc[pv];
            float4 wq = *(const float4*)(&psf[pv * 4]);
            int idx00 = (int)(e & 0x3FFFFFFFu);
            int dxo   = (int)((e >> 30) & 1u) << 7;    // +CH
            int dyo   = (int)(e >> 31) << 13;          // +WW*CH
            const ushort_t* bp = xb_img + idx00 + c0 + cg * 8;
            uint4 u00 = *(const uint4*)(bp);
            uint4 u01 = *(const uint4*)(bp + dxo);
            uint4 u10 = *(const uint4*)(bp + dyo);
            uint4 u11 = *(const uint4*)(bp + dxo + dyo);
            uint4 res;
#define CMB(fld) {                                                         \
            float lo = wq.x * bf2f(u00.fld & 0xffffu);                     \
            lo = fmaf(wq.y, bf2f(u01.fld & 0xffffu), lo);                  \
            lo = fmaf(wq.z, bf2f(u10.fld & 0xffffu), lo);                  \
            lo = fmaf(wq.w, bf2f(u11.fld & 0xffffu), lo);                  \
            float hi = wq.x * bf2f_hi(u00.fld);                            \
            hi = fmaf(wq.y, bf2f_hi(u01.fld), hi);                        \
            hi = fmaf(wq.z, bf2f_hi(u10.fld), hi);                        \
            hi = fmaf(wq.w, bf2f_hi(u11.fld), hi);                        \
            res.fld = (uint_t)f2bf(lo) | ((uint_t)f2bf(hi) << 16); }
            CMB(x); CMB(y); CMB(z); CMB(w);
#undef CMB
            *(uint4*)(&s[pix * RSE + swz(pix, t * 32 + cg * 8)]) = res;
        }
        __syncthreads();

        const ushort_t* wb = w2 + (size_t)chunk * 36 * 1024;
#pragma unroll 3
        for (int ks = 0; ks < 9; ++ks) {
            int rowA = wr * 32 + ll;
            int off  = swz(rowA, ks * 32 + lh * 8);
            short8v a0 = *(const short8v*)(&s[rowA * RSE + off]);
            short8v a1 = *(const short8v*)(&s[(rowA + 16) * RSE + off]);
            const ushort_t* wp = wb + (ks * 4 + lh) * 1024 + (wc * 64 + ll) * 8;
            short8v b0 = *(const short8v*)(wp);
            short8v b1 = *(const short8v*)(wp + 128);
            short8v b2 = *(const short8v*)(wp + 256);
            short8v b3 = *(const short8v*)(wp + 384);
            acc[0][0] = __builtin_amdgcn_mfma_f32_16x16x32_bf16(a0, b0, acc[0][0], 0, 0, 0);
            acc[0][1] = __builtin_amdgcn_mfma_f32_16x16x32_bf16(a0, b1, acc[0][1], 0, 0, 0);
            acc[0][2] = __builtin_amdgcn_mfma_f32_16x16x32_bf16(a0, b2, acc[0][2], 0, 0, 0);
            acc[0][3] = __builtin_amdgcn_mfma_f32_16x16x32_bf16(a0, b3, acc[0][3], 0, 0, 0);
            acc[1][0] = __builtin_amdgcn_mfma_f32_16x16x32_bf16(a1, b0, acc[1][0], 0, 0, 0);
            acc[1][1] = __builtin_amdgcn_mfma_f32_16x16x32_bf16(a1, b1, acc[1][1], 0, 0, 0);
            acc[1][2] = __builtin_amdgcn_mfma_f32_16x16x32_bf16(a1, b2, acc[1][2], 0, 0, 0);
            acc[1][3] = __builtin_amdgcn_mfma_f32_16x16x32_bf16(a1, b3, acc[1][3], 0, 0, 0);
        }
        __syncthreads();
    }

    // Epilogue: D col(oc)=ll, row(pix)=lh*4+reg
#pragma unroll
    for (int pi = 0; pi < 2; ++pi) {
#pragma unroll
        for (int oj = 0; oj < 4; ++oj) {
            int oc = wc * 64 + oj * 16 + ll;
            int w  = wr * 32 + pi * 16 + lh * 4;
            float bv = bias[oc];
            float4v a = acc[pi][oj];
            float* op = out + (((size_t)(b * CH + oc)) << 12) + (h << 6) + w;
            *(float4*)op = make_float4(a[0] + bv, a[1] + bv, a[2] + bv, a[3] + bv);
        }
    }
}

extern "C" void kernel_launch(void* const* d_in, const int* in_sizes, int n_in,
                              void* d_out, int out_size, void* d_ws, size_t ws_size,
                              hipStream_t stream) {
    const float* x        = (const float*)d_in[0];
    const float* offset_w = (const float*)d_in[1];
    const float* offset_b = (const float*)d_in[2];
    const float* mask_w   = (const float*)d_in[3];
    const float* mask_b   = (const float*)d_in[4];
    const float* weight   = (const float*)d_in[5];
    const float* bias     = (const float*)d_in[6];
    float* out = (float*)d_out;

    char* ws = (char*)d_ws;
    ushort_t* x_bf = (ushort_t*)ws;                        // 8,388,608 B
    ushort_t* w2   = (ushort_t*)(ws + 8388608);            //   294,912 B
    ushort_t* w2om = (ushort_t*)(ws + 8388608 + 294912);   //    73,728 B

    dim3 tb(32, 8, 1);
    dim3 tg(HWSZ / 32, CH / 32, BATCH);
    k_prep_x<<<tg, tb, 0, stream>>>(x, x_bf);
    k_prep_w<<<(CH * KDIM + 255) / 256, 256, 0, stream>>>(weight, w2);
    k_prep_w_om<<<(32 * KDIM + 255) / 256, 256, 0, stream>>>(offset_w, mask_w, w2om);

    int npix = BATCH * HWSZ;                               // 32768
    k_fused<<<npix / DP, 256, 0, stream>>>(x_bf, w2, w2om, offset_b, mask_b, bias, out);
}